// Round 5
// baseline (88.648 us; speedup 1.0000x reference)
//
#include <hip/hip_runtime.h>

#define M_BASIS 100
#define ROWS_PER_BLOCK 32
#define ROWS_PER_WAVE 8
constexpr float INV_TWO_PI = 0.15915494309189535f;

// Block = 256 threads = 4 waves; block b owns rows [32b, 32b+32).
// Wave w computes rows 32b+8w .. +8: lane l<50 owns j-pair {2l,2l+1} with
// basis params in registers (zero LDS traffic during compute). Results are
// staged in a 12800B LDS tile and streamed out as consecutive float4 per
// thread -> every HBM line is written fully, once, 128B-aligned.
__global__ __launch_bounds__(256) void cs_kernel(
    const float* __restrict__ theta,
    const float* __restrict__ basis_mu,
    const float* __restrict__ basis_sigma,
    float* __restrict__ out,
    int N)
{
    __shared__ float tile[ROWS_PER_BLOCK * M_BASIS];   // 12800 B

    const int tid  = threadIdx.x;
    const int lane = tid & 63;
    const int wave = tid >> 6;
    const bool active = (lane < (M_BASIS / 2));        // 50 lanes carry output

    // Basis params in registers: mu pair + both sigmas for j0=2l, j1=2l+1
    float4 mu2 = make_float4(0.f, 0.f, 0.f, 0.f);
    float4 sA  = make_float4(1.f, 0.f, 0.f, 1.f);
    float4 sB  = make_float4(1.f, 0.f, 0.f, 1.f);
    if (active) {
        mu2 = ((const float4*)basis_mu)[lane];
        sA  = ((const float4*)basis_sigma)[2 * lane];
        sB  = ((const float4*)basis_sigma)[2 * lane + 1];
    }

    const int row0 = blockIdx.x * ROWS_PER_BLOCK + wave * ROWS_PER_WAVE;

    #pragma unroll
    for (int k = 0; k < ROWS_PER_WAVE; ++k) {
        const int n = row0 + k;
        if (n < N) {
            const float* th = theta + n * 6;
            float2 e  = *(const float2*)(th);       // eta
            float2 qa = *(const float2*)(th + 2);   // q00 q01
            float2 qb = *(const float2*)(th + 4);   // q10 q11

            // P = -2Q; Sigma = sym(P^-1) = -0.5 * sym(Q^-1)
            float detQ = qa.x * qb.y - qa.y * qb.x;
            float r    = __builtin_amdgcn_rcpf(detQ);
            float h    = -0.5f * r;
            float S00  = qb.y * h;
            float S11  = qa.x * h;
            float S01  = (qa.y + qb.x) * (-0.5f * h);
            float Mu0  = S00 * e.x + S01 * e.y;
            float Mu1  = S01 * e.x + S11 * e.y;

            if (active) {
                // ---- j0 = 2*lane ----
                float c00 = S00 + sA.x, c01 = S01 + sA.y;
                float c10 = S01 + sA.z, c11 = S11 + sA.w;
                float d0 = Mu0 - mu2.x, d1 = Mu1 - mu2.y;
                float detC = c00 * c11 - c01 * c10;
                float rs   = __builtin_amdgcn_rsqf(detC);
                float invC = rs * rs;
                float num = d0 * d0 * c11 + d1 * d1 * c00 - d0 * d1 * (c01 + c10);
                float r0 = __expf(-0.5f * num * invC) * (INV_TWO_PI * rs);

                // ---- j1 = 2*lane + 1 ----
                float e00 = S00 + sB.x, e01 = S01 + sB.y;
                float e10 = S01 + sB.z, e11 = S11 + sB.w;
                float f0 = Mu0 - mu2.z, f1 = Mu1 - mu2.w;
                float detE = e00 * e11 - e01 * e10;
                float rsE  = __builtin_amdgcn_rsqf(detE);
                float invE = rsE * rsE;
                float numE = f0 * f0 * e11 + f1 * f1 * e00 - f0 * f1 * (e01 + e10);
                float r1 = __expf(-0.5f * numE * invE) * (INV_TWO_PI * rsE);

                ((float2*)(tile + (wave * ROWS_PER_WAVE + k) * M_BASIS))[lane] =
                    make_float2(r0, r1);
            }
        }
    }

    __syncthreads();

    // Dense, aligned block store: 32 rows * 100 floats = 800 float4.
    const int rows_valid = min(ROWS_PER_BLOCK, N - blockIdx.x * ROWS_PER_BLOCK);
    const int valid4 = rows_valid * (M_BASIS / 4);     // 25 float4 per row
    float4* obase = (float4*)(out + (size_t)blockIdx.x * ROWS_PER_BLOCK * M_BASIS);
    const float4* t4 = (const float4*)tile;
    for (int k = tid; k < valid4; k += 256) {
        obase[k] = t4[k];
    }
}

extern "C" void kernel_launch(void* const* d_in, const int* in_sizes, int n_in,
                              void* d_out, int out_size, void* d_ws, size_t ws_size,
                              hipStream_t stream) {
    const float* theta      = (const float*)d_in[0];   // [N,6]
    const float* basis_mu   = (const float*)d_in[1];   // [M,2]
    const float* basis_sig  = (const float*)d_in[2];   // [M,2,2]
    float* out = (float*)d_out;                        // [N,M]

    int N = in_sizes[0] / 6;
    int block = 256;
    int grid = (N + ROWS_PER_BLOCK - 1) / ROWS_PER_BLOCK;   // 4096 for N=131072
    hipLaunchKernelGGL(cs_kernel, dim3(grid), dim3(block), 0, stream,
                       theta, basis_mu, basis_sig, out, N);
}